// Round 9
// baseline (202.868 us; speedup 1.0000x reference)
//
#include <hip/hip_runtime.h>
#include <hip/hip_bf16.h>

#define B_ 4
#define L_ 1024
#define H_ 12
#define DK_ 64
#define FEA_ 768
#define MASKV (-32767.0f)

typedef __attribute__((ext_vector_type(8))) short bf16x8;
typedef __attribute__((ext_vector_type(4))) short s16x4;
typedef __attribute__((ext_vector_type(4))) float f32x4;
typedef unsigned int u32;

__device__ inline short f2bf(float x) {
  __hip_bfloat16 h = __float2bfloat16(x);   // HW cvt, RNE
  return __builtin_bit_cast(short, h);
}

// ---------------------------------------------------------------------------
// QKV projection: out[m][n] = sum_k X[m][k] * W[n][k] + b[n]
// M=4096, N=768, K=768. 64x64 tile, BK=64, 4 waves (2x2, each 32x32).
// Grid (64,12,3) = 2304 blocks -> 4+ blocks/CU (latency-bound fix).
// Double-buffered 32KB LDS, 1 barrier/k-step, loads issued before compute.
// Q,K stored [b][h][l][d] bf16; V stored transposed [b][h][d][l] bf16.
// ---------------------------------------------------------------------------
__global__ __launch_bounds__(256) void k_proj(
    const float* __restrict__ qx, const float* __restrict__ kx,
    const float* __restrict__ vx,
    const float* __restrict__ Wq, const float* __restrict__ bq,
    const float* __restrict__ Wk, const float* __restrict__ bk,
    const float* __restrict__ Wv, const float* __restrict__ bv,
    unsigned short* __restrict__ Qb, unsigned short* __restrict__ Kb,
    unsigned short* __restrict__ Vt)
{
  __shared__ short lA[2][64 * 64];
  __shared__ short lB[2][64 * 64];

  const int which = blockIdx.z;
  const float* __restrict__ A    = (which == 0) ? qx : (which == 1) ? kx : vx;
  const float* __restrict__ W    = (which == 0) ? Wq : (which == 1) ? Wk : Wv;
  const float* __restrict__ bias = (which == 0) ? bq : (which == 1) ? bk : bv;

  const int tid = threadIdx.x;
  const int lane = tid & 63;
  const int wid = tid >> 6;
  const int wr = wid >> 1, wc = wid & 1;
  const int m0 = blockIdx.x * 64;
  const int n0 = blockIdx.y * 64;
  const int g = lane >> 4, qc = lane & 15;
  const int row_s = tid >> 2;            // staging row 0..63
  const int cg = tid & 3;                // 16-float col group

  float4 rA[4], rB[4];

#define PROJ_LOAD(ktof)                                                        \
  {                                                                            \
    const float4* pa_ = (const float4*)(A + (size_t)(m0 + row_s) * FEA_ + (ktof) + cg * 16); \
    rA[0] = pa_[0]; rA[1] = pa_[1]; rA[2] = pa_[2]; rA[3] = pa_[3];            \
    const float4* pb_ = (const float4*)(W + (size_t)(n0 + row_s) * FEA_ + (ktof) + cg * 16); \
    rB[0] = pb_[0]; rB[1] = pb_[1]; rB[2] = pb_[2]; rB[3] = pb_[3];            \
  }

#define PROJ_WRITE(buf)                                                        \
  {                                                                            \
    bf16x8 a0_, a1_, b0_, b1_;                                                 \
    a0_[0] = f2bf(rA[0].x); a0_[1] = f2bf(rA[0].y); a0_[2] = f2bf(rA[0].z); a0_[3] = f2bf(rA[0].w); \
    a0_[4] = f2bf(rA[1].x); a0_[5] = f2bf(rA[1].y); a0_[6] = f2bf(rA[1].z); a0_[7] = f2bf(rA[1].w); \
    a1_[0] = f2bf(rA[2].x); a1_[1] = f2bf(rA[2].y); a1_[2] = f2bf(rA[2].z); a1_[3] = f2bf(rA[2].w); \
    a1_[4] = f2bf(rA[3].x); a1_[5] = f2bf(rA[3].y); a1_[6] = f2bf(rA[3].z); a1_[7] = f2bf(rA[3].w); \
    b0_[0] = f2bf(rB[0].x); b0_[1] = f2bf(rB[0].y); b0_[2] = f2bf(rB[0].z); b0_[3] = f2bf(rB[0].w); \
    b0_[4] = f2bf(rB[1].x); b0_[5] = f2bf(rB[1].y); b0_[6] = f2bf(rB[1].z); b0_[7] = f2bf(rB[1].w); \
    b1_[0] = f2bf(rB[2].x); b1_[1] = f2bf(rB[2].y); b1_[2] = f2bf(rB[2].z); b1_[3] = f2bf(rB[2].w); \
    b1_[4] = f2bf(rB[3].x); b1_[5] = f2bf(rB[3].y); b1_[6] = f2bf(rB[3].z); b1_[7] = f2bf(rB[3].w); \
    int c0_ = cg * 2, c1_ = cg * 2 + 1;                                        \
    *(bf16x8*)&lA[buf][row_s * 64 + ((c0_ ^ (row_s & 7)) << 3)] = a0_;         \
    *(bf16x8*)&lA[buf][row_s * 64 + ((c1_ ^ (row_s & 7)) << 3)] = a1_;         \
    *(bf16x8*)&lB[buf][row_s * 64 + ((c0_ ^ (row_s & 7)) << 3)] = b0_;         \
    *(bf16x8*)&lB[buf][row_s * 64 + ((c1_ ^ (row_s & 7)) << 3)] = b1_;         \
  }

  f32x4 acc[2][2];
#pragma unroll
  for (int i = 0; i < 2; i++)
#pragma unroll
    for (int j = 0; j < 2; j++) acc[i][j] = f32x4{0.f, 0.f, 0.f, 0.f};

  PROJ_LOAD(0);
  PROJ_WRITE(0);
  __syncthreads();

  for (int kt = 0; kt < 12; kt++) {
    const int cur = kt & 1, nxt = cur ^ 1;
    if (kt < 11) PROJ_LOAD((kt + 1) * 64);
#pragma unroll
    for (int s = 0; s < 2; s++) {
      bf16x8 af[2], bfr[2];
#pragma unroll
      for (int i = 0; i < 2; i++) {
        int ar = wr * 32 + i * 16 + qc;
        af[i] = *(const bf16x8*)&lA[cur][ar * 64 + (((s * 4 + g) ^ (ar & 7)) << 3)];
        int br = wc * 32 + i * 16 + qc;
        bfr[i] = *(const bf16x8*)&lB[cur][br * 64 + (((s * 4 + g) ^ (br & 7)) << 3)];
      }
#pragma unroll
      for (int i = 0; i < 2; i++)
#pragma unroll
        for (int j = 0; j < 2; j++)
          acc[i][j] = __builtin_amdgcn_mfma_f32_16x16x32_bf16(af[i], bfr[j], acc[i][j], 0, 0, 0);
    }
    if (kt < 11) PROJ_WRITE(nxt);
    __syncthreads();
  }

  const int cn0 = n0 + wc * 32;
  float bv2[2];
#pragma unroll
  for (int j = 0; j < 2; j++) bv2[j] = bias[cn0 + j * 16 + qc];

#pragma unroll
  for (int i = 0; i < 2; i++) {
    int m = m0 + wr * 32 + i * 16 + g * 4;
    int bb = m >> 10;
    int l = m & 1023;
#pragma unroll
    for (int j = 0; j < 2; j++) {
      int n = cn0 + j * 16 + qc;
      int hh = n >> 6, d = n & 63;
#pragma unroll
      for (int r = 0; r < 4; r++) {
        unsigned short v = (unsigned short)f2bf(acc[i][j][r] + bv2[j]);
        if (which == 2) {
          Vt[(((size_t)bb * H_ + hh) * DK_ + d) * L_ + (l + r)] = v;
        } else if (which == 0) {
          Qb[(((size_t)bb * H_ + hh) * L_ + (l + r)) * DK_ + d] = v;
        } else {
          Kb[(((size_t)bb * H_ + hh) * L_ + (l + r)) * DK_ + d] = v;
        }
      }
    }
  }
#undef PROJ_LOAD
#undef PROJ_WRITE
}

// ---------------------------------------------------------------------------
// Fused attention v8 (FROZEN, verified R8): R4 memory schedule + no-max
// softmax + XCD-aware block mapping + normal (L2-merged) scores stores.
// ---------------------------------------------------------------------------
__global__ __launch_bounds__(256, 3) void k_attn(
    const unsigned short* __restrict__ Qb, const unsigned short* __restrict__ Kb,
    const unsigned short* __restrict__ Vt,
    const float* __restrict__ preScores, const int* __restrict__ maskPAD,
    float* __restrict__ scoresOut, unsigned short* __restrict__ zp)
{
  __shared__ short lK[2][64 * 64];
  __shared__ short lV[2][64 * 64];
  __shared__ short lP[4][16 * 64];

  const int tid = threadIdx.x, lane = tid & 63, wid = tid >> 6;
  // XCD-aware decode: consecutive blockIdx round-robin across 8 XCDs.
  // XCD x gets bh in [x*6, x*6+6), all 16 q-tiles each. 768 = 8*6*16 exact.
  const int bi = blockIdx.x;
  const int slot = bi >> 3;                    // 0..95 within XCD
  const int bh_i = (bi & 7) * 6 + (slot >> 4); // 0..47
  const int qt = slot & 15;
  const int b = bh_i / H_;
  const int h = bh_i % H_;
  const int q0 = qt * 64;
  const int g = lane >> 4, qr = lane & 15;
  const int qrow = q0 + wid * 16 + qr;    // global q row in [0,1024)

  const size_t bh = (size_t)b * H_ + h;
  const unsigned short* __restrict__ Kbh = Kb + bh * L_ * DK_;
  const unsigned short* __restrict__ Vbh = Vt + bh * DK_ * L_;

  const int srow = lane >> 3;
  const int spos = lane & 7;

#define STAGE_KV(buf, kv0)                                                     \
  {                                                                            \
    _Pragma("unroll")                                                          \
    for (int i_ = 0; i_ < 2; i_++) {                                           \
      int r0_ = wid * 16 + i_ * 8;                                             \
      int row_ = r0_ + srow;                                                   \
      int cs_ = spos ^ (row_ & 7);                                             \
      __builtin_amdgcn_global_load_lds(                                        \
          (const __attribute__((address_space(1))) u32*)(Kbh +                 \
              (size_t)((kv0) + row_) * DK_ + cs_ * 8),                         \
          (__attribute__((address_space(3))) u32*)&lK[buf][r0_ * 64],          \
          16, 0, 0);                                                           \
      __builtin_amdgcn_global_load_lds(                                        \
          (const __attribute__((address_space(1))) u32*)(Vbh +                 \
              (size_t)row_ * L_ + (kv0) + cs_ * 8),                            \
          (__attribute__((address_space(3))) u32*)&lV[buf][r0_ * 64],          \
          16, 0, 0);                                                           \
    }                                                                          \
  }

  bf16x8 qf[2];
#pragma unroll
  for (int s = 0; s < 2; s++)
    qf[s] = *(const bf16x8*)(Qb + (bh * L_ + qrow) * DK_ + s * 32 + g * 8);

  f32x4 o[4];
#pragma unroll
  for (int i = 0; i < 4; i++) o[i] = f32x4{0.f, 0.f, 0.f, 0.f};
  float psum = 0.f;                       // per-lane partial sum (no-max)

  const size_t psBase = (bh * L_ + qrow) * L_;
  const size_t mkBase = ((size_t)b * L_ + qrow) * L_;

  // prologue: stage tile 0 (pinned oldest), prefetch ps/mask tile 0
  STAGE_KV(0, 0);
  __builtin_amdgcn_sched_barrier(0);
  float4 psn[4];
  int4 mkn[4];
#pragma unroll
  for (int i = 0; i < 4; i++) {
    psn[i] = *(const float4*)(preScores + psBase + i * 16 + g * 4);
    mkn[i] = *(const int4*)(maskPAD + mkBase + i * 16 + g * 4);
  }
  asm volatile("s_waitcnt vmcnt(8)" ::: "memory");
  __builtin_amdgcn_s_barrier();

  for (int kt = 0; kt < 16; kt++) {
    const int kv0 = kt * 64;
    const int cur = kt & 1, nxt = cur ^ 1;

    // issue next tile staging first; pin as oldest outstanding vmem
    if (kt < 15) {
      STAGE_KV(nxt, kv0 + 64);
    }
    __builtin_amdgcn_sched_barrier(0);

    // rotate ps/mask prefetch (depth-1, traffic-minimal)
    float4 psc[4]; int4 mkc[4];
#pragma unroll
    for (int i = 0; i < 4; i++) { psc[i] = psn[i]; mkc[i] = mkn[i]; }
    if (kt < 15) {
#pragma unroll
      for (int i = 0; i < 4; i++) {
        psn[i] = *(const float4*)(preScores + psBase + kv0 + 64 + i * 16 + g * 4);
        mkn[i] = *(const int4*)(maskPAD + mkBase + kv0 + 64 + i * 16 + g * 4);
      }
    }

    // S^T = K . Q^T from LDS
    f32x4 st[4];
#pragma unroll
    for (int i = 0; i < 4; i++) st[i] = f32x4{0.f, 0.f, 0.f, 0.f};
    __builtin_amdgcn_s_setprio(1);
#pragma unroll
    for (int s = 0; s < 2; s++) {
#pragma unroll
      for (int i = 0; i < 4; i++) {
        int kr = i * 16 + qr;
        bf16x8 kf = *(const bf16x8*)&lK[cur][kr * 64 + (((s * 4 + g) ^ (kr & 7)) << 3)];
        st[i] = __builtin_amdgcn_mfma_f32_16x16x32_bf16(kf, qf[s], st[i], 0, 0, 0);
      }
    }
    __builtin_amdgcn_s_setprio(0);

    // scale + preScores + mask; scores store (L2-merged); exp (no max);
    // pack P to wave-private LDS. No cross-lane ops in the loop.
#pragma unroll
    for (int i = 0; i < 4; i++) {
      int ko = i * 16 + g * 4;
      float4 sv;
      sv.x = (mkc[i].x == 0) ? MASKV : st[i][0] * 0.125f + psc[i].x;
      sv.y = (mkc[i].y == 0) ? MASKV : st[i][1] * 0.125f + psc[i].y;
      sv.z = (mkc[i].z == 0) ? MASKV : st[i][2] * 0.125f + psc[i].z;
      sv.w = (mkc[i].w == 0) ? MASKV : st[i][3] * 0.125f + psc[i].w;
      *(float4*)(scoresOut + psBase + kv0 + ko) = sv;
      float p0 = __expf(sv.x);
      float p1 = __expf(sv.y);
      float p2 = __expf(sv.z);
      float p3 = __expf(sv.w);
      psum += (p0 + p1) + (p2 + p3);
      s16x4 pw = {f2bf(p0), f2bf(p1), f2bf(p2), f2bf(p3)};
      int c = i * 2 + (g >> 1);
      *(s16x4*)&lP[wid][qr * 64 + ((c ^ (qr & 7)) << 3) + ((g & 1) << 2)] = pw;
    }

    // O^T += Vt_strip . P^T from LDS
    __builtin_amdgcn_s_setprio(1);
#pragma unroll
    for (int s = 0; s < 2; s++) {
      bf16x8 pf = *(const bf16x8*)&lP[wid][qr * 64 + (((s * 4 + g) ^ (qr & 7)) << 3)];
#pragma unroll
      for (int i = 0; i < 4; i++) {
        int vr = i * 16 + qr;
        bf16x8 vf = *(const bf16x8*)&lV[cur][vr * 64 + (((s * 4 + g) ^ (vr & 7)) << 3)];
        o[i] = __builtin_amdgcn_mfma_f32_16x16x32_bf16(vf, pf, o[i], 0, 0, 0);
      }
    }
    __builtin_amdgcn_s_setprio(0);

    // counted barrier: wait only the 4 staging loads (oldest); scores stores
    // (4) and ps/mask prefetch (8) stay in flight.
    asm volatile("s_waitcnt vmcnt(12)" ::: "memory");
    __builtin_amdgcn_s_barrier();
  }

  // final row-sum reduce (2 shuffles) + normalize + write z_pre
  psum += __shfl_xor(psum, 16);
  psum += __shfl_xor(psum, 32);
  float inv = 1.f / psum;
  size_t zr = ((size_t)b * L_ + qrow) * FEA_ + (size_t)h * DK_;
#pragma unroll
  for (int i = 0; i < 4; i++) {
    s16x4 zw = {f2bf(o[i][0] * inv), f2bf(o[i][1] * inv),
                f2bf(o[i][2] * inv), f2bf(o[i][3] * inv)};
    *(s16x4*)((unsigned short*)zp + zr + i * 16 + g * 4) = zw;
  }
#undef STAGE_KV
}

// ---------------------------------------------------------------------------
// Output projection: out[m][n] = sum_k zp[m][k] * Wo[n][k] + bo[n], fp32 out.
// 64x64 tile, 4 waves (2x2, each 32x32). Grid (64,12) = 768 blocks ->
// 3 blocks/CU (was 192 blocks = 0.75/CU). Double-buffered 32KB LDS.
// ---------------------------------------------------------------------------
__global__ __launch_bounds__(256) void k_oproj(
    const unsigned short* __restrict__ zp,
    const float* __restrict__ Wo, const float* __restrict__ bo,
    float* __restrict__ out)
{
  __shared__ short lA[2][64 * 64];
  __shared__ short lB[2][64 * 64];

  const int tid = threadIdx.x;
  const int lane = tid & 63;
  const int wid = tid >> 6;
  const int wr = wid >> 1, wc = wid & 1;
  const int m0 = blockIdx.x * 64;
  const int n0 = blockIdx.y * 64;
  const int g = lane >> 4, qc = lane & 15;
  const int row_s = tid >> 2;
  const int cg = tid & 3;

  bf16x8 rA[2];
  float4 rB[4];

#define OP_LOAD(ktof)                                                          \
  {                                                                            \
    const bf16x8* pa_ = (const bf16x8*)(zp + (size_t)(m0 + row_s) * FEA_ + (ktof) + cg * 16); \
    rA[0] = pa_[0]; rA[1] = pa_[1];                                            \
    const float4* pb_ = (const float4*)(Wo + (size_t)(n0 + row_s) * FEA_ + (ktof) + cg * 16); \
    rB[0] = pb_[0]; rB[1] = pb_[1]; rB[2] = pb_[2]; rB[3] = pb_[3];            \
  }

#define OP_WRITE(buf)                                                          \
  {                                                                            \
    int c0_ = cg * 2, c1_ = cg * 2 + 1;                                        \
    *(bf16x8*)&lA[buf][row_s * 64 + ((c0_ ^ (row_s & 7)) << 3)] = rA[0];       \
    *(bf16x8*)&lA[buf][row_s * 64 + ((c1_ ^ (row_s & 7)) << 3)] = rA[1];       \
    bf16x8 b0_, b1_;                                                           \
    b0_[0] = f2bf(rB[0].x); b0_[1] = f2bf(rB[0].y); b0_[2] = f2bf(rB[0].z); b0_[3] = f2bf(rB[0].w); \
    b0_[4] = f2bf(rB[1].x); b0_[5] = f2bf(rB[1].y); b0_[6] = f2bf(rB[1].z); b0_[7] = f2bf(rB[1].w); \
    b1_[0] = f2bf(rB[2].x); b1_[1] = f2bf(rB[2].y); b1_[2] = f2bf(rB[2].z); b1_[3] = f2bf(rB[2].w); \
    b1_[4] = f2bf(rB[3].x); b1_[5] = f2bf(rB[3].y); b1_[6] = f2bf(rB[3].z); b1_[7] = f2bf(rB[3].w); \
    *(bf16x8*)&lB[buf][row_s * 64 + ((c0_ ^ (row_s & 7)) << 3)] = b0_;         \
    *(bf16x8*)&lB[buf][row_s * 64 + ((c1_ ^ (row_s & 7)) << 3)] = b1_;         \
  }

  f32x4 acc[2][2];
#pragma unroll
  for (int i = 0; i < 2; i++)
#pragma unroll
    for (int j = 0; j < 2; j++) acc[i][j] = f32x4{0.f, 0.f, 0.f, 0.f};

  OP_LOAD(0);
  OP_WRITE(0);
  __syncthreads();

  for (int kt = 0; kt < 12; kt++) {
    const int cur = kt & 1, nxt = cur ^ 1;
    if (kt < 11) OP_LOAD((kt + 1) * 64);
#pragma unroll
    for (int s = 0; s < 2; s++) {
      bf16x8 af[2], bfr[2];
#pragma unroll
      for (int i = 0; i < 2; i++) {
        int ar = wr * 32 + i * 16 + qc;
        af[i] = *(const bf16x8*)&lA[cur][ar * 64 + (((s * 4 + g) ^ (ar & 7)) << 3)];
        int br = wc * 32 + i * 16 + qc;
        bfr[i] = *(const bf16x8*)&lB[cur][br * 64 + (((s * 4 + g) ^ (br & 7)) << 3)];
      }
#pragma unroll
      for (int i = 0; i < 2; i++)
#pragma unroll
        for (int j = 0; j < 2; j++)
          acc[i][j] = __builtin_amdgcn_mfma_f32_16x16x32_bf16(af[i], bfr[j], acc[i][j], 0, 0, 0);
    }
    if (kt < 11) OP_WRITE(nxt);
    __syncthreads();
  }

  const int cn0 = n0 + wc * 32;
  float bv2[2];
#pragma unroll
  for (int j = 0; j < 2; j++) bv2[j] = bo[cn0 + j * 16 + qc];

#pragma unroll
  for (int i = 0; i < 2; i++) {
    int m = m0 + wr * 32 + i * 16 + g * 4;
#pragma unroll
    for (int j = 0; j < 2; j++) {
      int n = cn0 + j * 16 + qc;
#pragma unroll
      for (int r = 0; r < 4; r++) {
        out[(size_t)(m + r) * FEA_ + n] = acc[i][j][r] + bv2[j];
      }
    }
  }
#undef OP_LOAD
#undef OP_WRITE
}

extern "C" void kernel_launch(void* const* d_in, const int* in_sizes, int n_in,
                              void* d_out, int out_size, void* d_ws, size_t ws_size,
                              hipStream_t stream) {
  const float* qx = (const float*)d_in[0];
  const float* kx = (const float*)d_in[1];
  const float* vx = (const float*)d_in[2];
  const float* preScores = (const float*)d_in[3];
  const int* maskPAD = (const int*)d_in[4];
  const float* Wq = (const float*)d_in[5];
  const float* bq = (const float*)d_in[6];
  const float* Wk = (const float*)d_in[7];
  const float* bk = (const float*)d_in[8];
  const float* Wv = (const float*)d_in[9];
  const float* bv = (const float*)d_in[10];
  const float* Wo = (const float*)d_in[11];
  const float* bo = (const float*)d_in[12];

  float* z_out = (float*)d_out;
  float* scores_out = z_out + (size_t)B_ * L_ * FEA_;

  unsigned short* Qb = (unsigned short*)d_ws;
  unsigned short* Kb = Qb + (size_t)B_ * H_ * L_ * DK_;
  unsigned short* Vt = Kb + (size_t)B_ * H_ * L_ * DK_;
  unsigned short* zp = Vt + (size_t)B_ * H_ * L_ * DK_;

  k_proj<<<dim3(64, 12, 3), 256, 0, stream>>>(qx, kx, vx, Wq, bq, Wk, bk, Wv, bv,
                                              Qb, Kb, Vt);
  k_attn<<<dim3(8 * 6 * 16, 1, 1), 256, 0, stream>>>(Qb, Kb, Vt, preScores,
                                                     maskPAD, scores_out, zp);
  k_oproj<<<dim3(64, 12), 256, 0, stream>>>(zp, Wo, bo, z_out);
}

// Round 11
// 181.633 us; speedup vs baseline: 1.1169x; 1.1169x over previous
//
#include <hip/hip_runtime.h>
#include <hip/hip_bf16.h>

#define B_ 4
#define L_ 1024
#define H_ 12
#define DK_ 64
#define FEA_ 768
#define MASKV (-32767.0f)

typedef __attribute__((ext_vector_type(8))) short bf16x8;
typedef __attribute__((ext_vector_type(4))) short s16x4;
typedef __attribute__((ext_vector_type(4))) float f32x4;
typedef unsigned int u32;

__device__ inline short f2bf(float x) {
  __hip_bfloat16 h = __float2bfloat16(x);   // HW cvt, RNE
  return __builtin_bit_cast(short, h);
}

// sizes (floats)
#define SZX  (4 * 1024 * 768)      // qx/kx/vx each: 3145728
#define SZW  (768 * 768)           // each W: 589824

// ---------------------------------------------------------------------------
// fp32 -> bf16 convert pass: qx,kx,vx,Wq,Wk,Wv -> contiguous bf16 scratch.
// (Wo is NOT converted: its consumer k_oproj runs after k_attn, which
// overwrites the scratch region. R10's NaN was exactly that lifetime bug.)
// ---------------------------------------------------------------------------
__global__ __launch_bounds__(256) void k_cvt(
    const float* __restrict__ qx, const float* __restrict__ kx,
    const float* __restrict__ vx,
    const float* __restrict__ Wq, const float* __restrict__ Wk,
    const float* __restrict__ Wv,
    unsigned short* __restrict__ dst)
{
  const size_t SZX4 = SZX / 4, SZW4 = SZW / 4;
  const size_t total4 = 3 * SZX4 + 3 * SZW4;
  for (size_t i4 = (size_t)blockIdx.x * 256 + threadIdx.x; i4 < total4;
       i4 += (size_t)gridDim.x * 256) {
    const float* src; size_t o4; size_t db;
    if (i4 < SZX4)               { src = qx; o4 = i4;               db = 0; }
    else if (i4 < 2 * SZX4)      { src = kx; o4 = i4 - SZX4;        db = (size_t)SZX; }
    else if (i4 < 3 * SZX4)      { src = vx; o4 = i4 - 2 * SZX4;    db = 2 * (size_t)SZX; }
    else if (i4 < 3 * SZX4 + SZW4)     { src = Wq; o4 = i4 - 3 * SZX4;            db = 3 * (size_t)SZX; }
    else if (i4 < 3 * SZX4 + 2 * SZW4) { src = Wk; o4 = i4 - 3 * SZX4 - SZW4;     db = 3 * (size_t)SZX + SZW; }
    else                               { src = Wv; o4 = i4 - 3 * SZX4 - 2 * SZW4; db = 3 * (size_t)SZX + 2 * (size_t)SZW; }
    float4 v = ((const float4*)src)[o4];
    s16x4 r = {f2bf(v.x), f2bf(v.y), f2bf(v.z), f2bf(v.w)};
    *(s16x4*)(dst + db + o4 * 4) = r;
  }
}

// ---------------------------------------------------------------------------
// QKV projection (pure bf16): out[m][n] = sum_k A[m][k]*W[n][k] + b[n].
// 64x64 tile, BK=64, 4 waves (2x2, each 32x32). global_load_lds staging
// (pre-swizzled source, linear LDS dest), dbuf 32KB.
// Grid (64,12,3) = 2304 blocks. Q,K -> [b][h][l][d]; V -> [b][h][d][l].
// ---------------------------------------------------------------------------
__global__ __launch_bounds__(256) void k_proj(
    const unsigned short* __restrict__ qxb, const unsigned short* __restrict__ kxb,
    const unsigned short* __restrict__ vxb,
    const unsigned short* __restrict__ Wqb, const unsigned short* __restrict__ Wkb,
    const unsigned short* __restrict__ Wvb,
    const float* __restrict__ bq, const float* __restrict__ bk,
    const float* __restrict__ bv,
    unsigned short* __restrict__ Qb, unsigned short* __restrict__ Kb,
    unsigned short* __restrict__ Vt)
{
  __shared__ short lA[2][64 * 64];
  __shared__ short lB[2][64 * 64];

  const int which = blockIdx.z;
  const unsigned short* __restrict__ Ab = (which == 0) ? qxb : (which == 1) ? kxb : vxb;
  const unsigned short* __restrict__ Wb = (which == 0) ? Wqb : (which == 1) ? Wkb : Wvb;
  const float* __restrict__ bias = (which == 0) ? bq : (which == 1) ? bk : bv;

  const int tid = threadIdx.x;
  const int lane = tid & 63;
  const int wid = tid >> 6;
  const int wr = wid >> 1, wc = wid & 1;
  const int m0 = blockIdx.x * 64;
  const int n0 = blockIdx.y * 64;
  const int g = lane >> 4, qc = lane & 15;
  const int srow = lane >> 3;
  const int spos = lane & 7;

#define PSTAGE(buf, ktof)                                                      \
  {                                                                            \
    _Pragma("unroll")                                                          \
    for (int i_ = 0; i_ < 2; i_++) {                                           \
      int r0_ = wid * 16 + i_ * 8;                                             \
      int row_ = r0_ + srow;                                                   \
      int cs_ = spos ^ (row_ & 7);                                             \
      __builtin_amdgcn_global_load_lds(                                        \
          (const __attribute__((address_space(1))) u32*)(Ab +                  \
              (size_t)(m0 + row_) * FEA_ + (ktof) + cs_ * 8),                  \
          (__attribute__((address_space(3))) u32*)&lA[buf][r0_ * 64],          \
          16, 0, 0);                                                           \
      __builtin_amdgcn_global_load_lds(                                        \
          (const __attribute__((address_space(1))) u32*)(Wb +                  \
              (size_t)(n0 + row_) * FEA_ + (ktof) + cs_ * 8),                  \
          (__attribute__((address_space(3))) u32*)&lB[buf][r0_ * 64],          \
          16, 0, 0);                                                           \
    }                                                                          \
  }

  f32x4 acc[2][2];
#pragma unroll
  for (int i = 0; i < 2; i++)
#pragma unroll
    for (int j = 0; j < 2; j++) acc[i][j] = f32x4{0.f, 0.f, 0.f, 0.f};

  PSTAGE(0, 0);
  asm volatile("s_waitcnt vmcnt(0)" ::: "memory");
  __builtin_amdgcn_s_barrier();

  for (int kt = 0; kt < 12; kt++) {
    const int cur = kt & 1, nxt = cur ^ 1;
    if (kt < 11) PSTAGE(nxt, (kt + 1) * 64);
    __builtin_amdgcn_sched_barrier(0);
    __builtin_amdgcn_s_setprio(1);
#pragma unroll
    for (int s = 0; s < 2; s++) {
      bf16x8 af[2], bfr[2];
#pragma unroll
      for (int i = 0; i < 2; i++) {
        int ar = wr * 32 + i * 16 + qc;
        af[i] = *(const bf16x8*)&lA[cur][ar * 64 + (((s * 4 + g) ^ (ar & 7)) << 3)];
        int br = wc * 32 + i * 16 + qc;
        bfr[i] = *(const bf16x8*)&lB[cur][br * 64 + (((s * 4 + g) ^ (br & 7)) << 3)];
      }
#pragma unroll
      for (int i = 0; i < 2; i++)
#pragma unroll
        for (int j = 0; j < 2; j++)
          acc[i][j] = __builtin_amdgcn_mfma_f32_16x16x32_bf16(af[i], bfr[j], acc[i][j], 0, 0, 0);
    }
    __builtin_amdgcn_s_setprio(0);
    asm volatile("s_waitcnt vmcnt(0)" ::: "memory");
    __builtin_amdgcn_s_barrier();
  }

  const int cn0 = n0 + wc * 32;
  float bv2[2];
#pragma unroll
  for (int j = 0; j < 2; j++) bv2[j] = bias[cn0 + j * 16 + qc];

#pragma unroll
  for (int i = 0; i < 2; i++) {
    int m = m0 + wr * 32 + i * 16 + g * 4;
    int bb = m >> 10;
    int l = m & 1023;
#pragma unroll
    for (int j = 0; j < 2; j++) {
      int n = cn0 + j * 16 + qc;
      int hh = n >> 6, d = n & 63;
#pragma unroll
      for (int r = 0; r < 4; r++) {
        unsigned short v = (unsigned short)f2bf(acc[i][j][r] + bv2[j]);
        if (which == 2) {
          Vt[(((size_t)bb * H_ + hh) * DK_ + d) * L_ + (l + r)] = v;
        } else if (which == 0) {
          Qb[(((size_t)bb * H_ + hh) * L_ + (l + r)) * DK_ + d] = v;
        } else {
          Kb[(((size_t)bb * H_ + hh) * L_ + (l + r)) * DK_ + d] = v;
        }
      }
    }
  }
#undef PSTAGE
}

// ---------------------------------------------------------------------------
// Fused attention v8 (FROZEN, verified R8): R4 memory schedule + no-max
// softmax + XCD-aware block mapping + normal (L2-merged) scores stores.
// ---------------------------------------------------------------------------
__global__ __launch_bounds__(256, 3) void k_attn(
    const unsigned short* __restrict__ Qb, const unsigned short* __restrict__ Kb,
    const unsigned short* __restrict__ Vt,
    const float* __restrict__ preScores, const int* __restrict__ maskPAD,
    float* __restrict__ scoresOut, unsigned short* __restrict__ zp)
{
  __shared__ short lK[2][64 * 64];
  __shared__ short lV[2][64 * 64];
  __shared__ short lP[4][16 * 64];

  const int tid = threadIdx.x, lane = tid & 63, wid = tid >> 6;
  const int bi = blockIdx.x;
  const int slot = bi >> 3;                    // 0..95 within XCD
  const int bh_i = (bi & 7) * 6 + (slot >> 4); // 0..47
  const int qt = slot & 15;
  const int b = bh_i / H_;
  const int h = bh_i % H_;
  const int q0 = qt * 64;
  const int g = lane >> 4, qr = lane & 15;
  const int qrow = q0 + wid * 16 + qr;

  const size_t bh = (size_t)b * H_ + h;
  const unsigned short* __restrict__ Kbh = Kb + bh * L_ * DK_;
  const unsigned short* __restrict__ Vbh = Vt + bh * DK_ * L_;

  const int srow = lane >> 3;
  const int spos = lane & 7;

#define STAGE_KV(buf, kv0)                                                     \
  {                                                                            \
    _Pragma("unroll")                                                          \
    for (int i_ = 0; i_ < 2; i_++) {                                           \
      int r0_ = wid * 16 + i_ * 8;                                             \
      int row_ = r0_ + srow;                                                   \
      int cs_ = spos ^ (row_ & 7);                                             \
      __builtin_amdgcn_global_load_lds(                                        \
          (const __attribute__((address_space(1))) u32*)(Kbh +                 \
              (size_t)((kv0) + row_) * DK_ + cs_ * 8),                         \
          (__attribute__((address_space(3))) u32*)&lK[buf][r0_ * 64],          \
          16, 0, 0);                                                           \
      __builtin_amdgcn_global_load_lds(                                        \
          (const __attribute__((address_space(1))) u32*)(Vbh +                 \
              (size_t)row_ * L_ + (kv0) + cs_ * 8),                            \
          (__attribute__((address_space(3))) u32*)&lV[buf][r0_ * 64],          \
          16, 0, 0);                                                           \
    }                                                                          \
  }

  bf16x8 qf[2];
#pragma unroll
  for (int s = 0; s < 2; s++)
    qf[s] = *(const bf16x8*)(Qb + (bh * L_ + qrow) * DK_ + s * 32 + g * 8);

  f32x4 o[4];
#pragma unroll
  for (int i = 0; i < 4; i++) o[i] = f32x4{0.f, 0.f, 0.f, 0.f};
  float psum = 0.f;

  const size_t psBase = (bh * L_ + qrow) * L_;
  const size_t mkBase = ((size_t)b * L_ + qrow) * L_;

  STAGE_KV(0, 0);
  __builtin_amdgcn_sched_barrier(0);
  float4 psn[4];
  int4 mkn[4];
#pragma unroll
  for (int i = 0; i < 4; i++) {
    psn[i] = *(const float4*)(preScores + psBase + i * 16 + g * 4);
    mkn[i] = *(const int4*)(maskPAD + mkBase + i * 16 + g * 4);
  }
  asm volatile("s_waitcnt vmcnt(8)" ::: "memory");
  __builtin_amdgcn_s_barrier();

  for (int kt = 0; kt < 16; kt++) {
    const int kv0 = kt * 64;
    const int cur = kt & 1, nxt = cur ^ 1;

    if (kt < 15) {
      STAGE_KV(nxt, kv0 + 64);
    }
    __builtin_amdgcn_sched_barrier(0);

    float4 psc[4]; int4 mkc[4];
#pragma unroll
    for (int i = 0; i < 4; i++) { psc[i] = psn[i]; mkc[i] = mkn[i]; }
    if (kt < 15) {
#pragma unroll
      for (int i = 0; i < 4; i++) {
        psn[i] = *(const float4*)(preScores + psBase + kv0 + 64 + i * 16 + g * 4);
        mkn[i] = *(const int4*)(maskPAD + mkBase + kv0 + 64 + i * 16 + g * 4);
      }
    }

    f32x4 st[4];
#pragma unroll
    for (int i = 0; i < 4; i++) st[i] = f32x4{0.f, 0.f, 0.f, 0.f};
    __builtin_amdgcn_s_setprio(1);
#pragma unroll
    for (int s = 0; s < 2; s++) {
#pragma unroll
      for (int i = 0; i < 4; i++) {
        int kr = i * 16 + qr;
        bf16x8 kf = *(const bf16x8*)&lK[cur][kr * 64 + (((s * 4 + g) ^ (kr & 7)) << 3)];
        st[i] = __builtin_amdgcn_mfma_f32_16x16x32_bf16(kf, qf[s], st[i], 0, 0, 0);
      }
    }
    __builtin_amdgcn_s_setprio(0);

#pragma unroll
    for (int i = 0; i < 4; i++) {
      int ko = i * 16 + g * 4;
      float4 sv;
      sv.x = (mkc[i].x == 0) ? MASKV : st[i][0] * 0.125f + psc[i].x;
      sv.y = (mkc[i].y == 0) ? MASKV : st[i][1] * 0.125f + psc[i].y;
      sv.z = (mkc[i].z == 0) ? MASKV : st[i][2] * 0.125f + psc[i].z;
      sv.w = (mkc[i].w == 0) ? MASKV : st[i][3] * 0.125f + psc[i].w;
      *(float4*)(scoresOut + psBase + kv0 + ko) = sv;
      float p0 = __expf(sv.x);
      float p1 = __expf(sv.y);
      float p2 = __expf(sv.z);
      float p3 = __expf(sv.w);
      psum += (p0 + p1) + (p2 + p3);
      s16x4 pw = {f2bf(p0), f2bf(p1), f2bf(p2), f2bf(p3)};
      int c = i * 2 + (g >> 1);
      *(s16x4*)&lP[wid][qr * 64 + ((c ^ (qr & 7)) << 3) + ((g & 1) << 2)] = pw;
    }

    __builtin_amdgcn_s_setprio(1);
#pragma unroll
    for (int s = 0; s < 2; s++) {
      bf16x8 pf = *(const bf16x8*)&lP[wid][qr * 64 + (((s * 4 + g) ^ (qr & 7)) << 3)];
#pragma unroll
      for (int i = 0; i < 4; i++) {
        int vr = i * 16 + qr;
        bf16x8 vf = *(const bf16x8*)&lV[cur][vr * 64 + (((s * 4 + g) ^ (vr & 7)) << 3)];
        o[i] = __builtin_amdgcn_mfma_f32_16x16x32_bf16(vf, pf, o[i], 0, 0, 0);
      }
    }
    __builtin_amdgcn_s_setprio(0);

    asm volatile("s_waitcnt vmcnt(12)" ::: "memory");
    __builtin_amdgcn_s_barrier();
  }

  psum += __shfl_xor(psum, 16);
  psum += __shfl_xor(psum, 32);
  float inv = 1.f / psum;
  size_t zr = ((size_t)b * L_ + qrow) * FEA_ + (size_t)h * DK_;
#pragma unroll
  for (int i = 0; i < 4; i++) {
    s16x4 zw = {f2bf(o[i][0] * inv), f2bf(o[i][1] * inv),
                f2bf(o[i][2] * inv), f2bf(o[i][3] * inv)};
    *(s16x4*)((unsigned short*)zp + zr + i * 16 + g * 4) = zw;
  }
#undef STAGE_KV
}

// ---------------------------------------------------------------------------
// Output projection (R9-verified): out = zp @ Wo^T + bo, fp32 out.
// 64x64 tile, register staging (zp bf16 direct; Wo fp32 cvt in staging —
// Wo can't be pre-converted: scratch is clobbered by k_attn). Grid (64,12).
// ---------------------------------------------------------------------------
__global__ __launch_bounds__(256) void k_oproj(
    const unsigned short* __restrict__ zp,
    const float* __restrict__ Wo, const float* __restrict__ bo,
    float* __restrict__ out)
{
  __shared__ short lA[2][64 * 64];
  __shared__ short lB[2][64 * 64];

  const int tid = threadIdx.x;
  const int lane = tid & 63;
  const int wid = tid >> 6;
  const int wr = wid >> 1, wc = wid & 1;
  const int m0 = blockIdx.x * 64;
  const int n0 = blockIdx.y * 64;
  const int g = lane >> 4, qc = lane & 15;
  const int row_s = tid >> 2;
  const int cg = tid & 3;

  bf16x8 rA[2];
  float4 rB[4];

#define OP_LOAD(ktof)                                                          \
  {                                                                            \
    const bf16x8* pa_ = (const bf16x8*)(zp + (size_t)(m0 + row_s) * FEA_ + (ktof) + cg * 16); \
    rA[0] = pa_[0]; rA[1] = pa_[1];                                            \
    const float4* pb_ = (const float4*)(Wo + (size_t)(n0 + row_s) * FEA_ + (ktof) + cg * 16); \
    rB[0] = pb_[0]; rB[1] = pb_[1]; rB[2] = pb_[2]; rB[3] = pb_[3];            \
  }

#define OP_WRITE(buf)                                                          \
  {                                                                            \
    int c0_ = cg * 2, c1_ = cg * 2 + 1;                                        \
    *(bf16x8*)&lA[buf][row_s * 64 + ((c0_ ^ (row_s & 7)) << 3)] = rA[0];       \
    *(bf16x8*)&lA[buf][row_s * 64 + ((c1_ ^ (row_s & 7)) << 3)] = rA[1];       \
    bf16x8 b0_, b1_;                                                           \
    b0_[0] = f2bf(rB[0].x); b0_[1] = f2bf(rB[0].y); b0_[2] = f2bf(rB[0].z); b0_[3] = f2bf(rB[0].w); \
    b0_[4] = f2bf(rB[1].x); b0_[5] = f2bf(rB[1].y); b0_[6] = f2bf(rB[1].z); b0_[7] = f2bf(rB[1].w); \
    b1_[0] = f2bf(rB[2].x); b1_[1] = f2bf(rB[2].y); b1_[2] = f2bf(rB[2].z); b1_[3] = f2bf(rB[2].w); \
    b1_[4] = f2bf(rB[3].x); b1_[5] = f2bf(rB[3].y); b1_[6] = f2bf(rB[3].z); b1_[7] = f2bf(rB[3].w); \
    *(bf16x8*)&lB[buf][row_s * 64 + ((c0_ ^ (row_s & 7)) << 3)] = b0_;         \
    *(bf16x8*)&lB[buf][row_s * 64 + ((c1_ ^ (row_s & 7)) << 3)] = b1_;         \
  }

  f32x4 acc[2][2];
#pragma unroll
  for (int i = 0; i < 2; i++)
#pragma unroll
    for (int j = 0; j < 2; j++) acc[i][j] = f32x4{0.f, 0.f, 0.f, 0.f};

  OP_LOAD(0);
  OP_WRITE(0);
  __syncthreads();

  for (int kt = 0; kt < 12; kt++) {
    const int cur = kt & 1, nxt = cur ^ 1;
    if (kt < 11) OP_LOAD((kt + 1) * 64);
#pragma unroll
    for (int s = 0; s < 2; s++) {
      bf16x8 af[2], bfr[2];
#pragma unroll
      for (int i = 0; i < 2; i++) {
        int ar = wr * 32 + i * 16 + qc;
        af[i] = *(const bf16x8*)&lA[cur][ar * 64 + (((s * 4 + g) ^ (ar & 7)) << 3)];
        int br = wc * 32 + i * 16 + qc;
        bfr[i] = *(const bf16x8*)&lB[cur][br * 64 + (((s * 4 + g) ^ (br & 7)) << 3)];
      }
#pragma unroll
      for (int i = 0; i < 2; i++)
#pragma unroll
        for (int j = 0; j < 2; j++)
          acc[i][j] = __builtin_amdgcn_mfma_f32_16x16x32_bf16(af[i], bfr[j], acc[i][j], 0, 0, 0);
    }
    if (kt < 11) OP_WRITE(nxt);
    __syncthreads();
  }

  const int cn0 = n0 + wc * 32;
  float bv2[2];
#pragma unroll
  for (int j = 0; j < 2; j++) bv2[j] = bo[cn0 + j * 16 + qc];

#pragma unroll
  for (int i = 0; i < 2; i++) {
    int m = m0 + wr * 32 + i * 16 + g * 4;
#pragma unroll
    for (int j = 0; j < 2; j++) {
      int n = cn0 + j * 16 + qc;
#pragma unroll
      for (int r = 0; r < 4; r++) {
        out[(size_t)(m + r) * FEA_ + n] = acc[i][j][r] + bv2[j];
      }
    }
  }
#undef OP_LOAD
#undef OP_WRITE
}

extern "C" void kernel_launch(void* const* d_in, const int* in_sizes, int n_in,
                              void* d_out, int out_size, void* d_ws, size_t ws_size,
                              hipStream_t stream) {
  const float* qx = (const float*)d_in[0];
  const float* kx = (const float*)d_in[1];
  const float* vx = (const float*)d_in[2];
  const float* preScores = (const float*)d_in[3];
  const int* maskPAD = (const int*)d_in[4];
  const float* Wq = (const float*)d_in[5];
  const float* bq = (const float*)d_in[6];
  const float* Wk = (const float*)d_in[7];
  const float* bk = (const float*)d_in[8];
  const float* Wv = (const float*)d_in[9];
  const float* bv = (const float*)d_in[10];
  const float* Wo = (const float*)d_in[11];
  const float* bo = (const float*)d_in[12];

  float* z_out = (float*)d_out;
  float* scores_out = z_out + (size_t)B_ * L_ * FEA_;

  unsigned short* Qb = (unsigned short*)d_ws;
  unsigned short* Kb = Qb + (size_t)B_ * H_ * L_ * DK_;
  unsigned short* Vt = Kb + (size_t)B_ * H_ * L_ * DK_;
  unsigned short* zp = Vt + (size_t)B_ * H_ * L_ * DK_;

  // bf16 scratch carved from the TAIL of the scores output region. Holds
  // ONLY tensors consumed by k_proj (which completes before k_attn starts,
  // so k_attn's scores writes can't clobber live data). 11206656 shorts =
  // 5603328 floats at offset 50331648 - 5603328 (16B aligned).
  unsigned short* cvtb = (unsigned short*)(scores_out + (50331648 - 5603328));
  const unsigned short* qxb = cvtb;
  const unsigned short* kxb = cvtb + (size_t)SZX;
  const unsigned short* vxb = cvtb + 2 * (size_t)SZX;
  const unsigned short* Wqb = cvtb + 3 * (size_t)SZX;
  const unsigned short* Wkb = cvtb + 3 * (size_t)SZX + (size_t)SZW;
  const unsigned short* Wvb = cvtb + 3 * (size_t)SZX + 2 * (size_t)SZW;

  k_cvt<<<dim3(1024), 256, 0, stream>>>(qx, kx, vx, Wq, Wk, Wv, cvtb);
  k_proj<<<dim3(64, 12, 3), 256, 0, stream>>>(qxb, kxb, vxb, Wqb, Wkb, Wvb,
                                              bq, bk, bv, Qb, Kb, Vt);
  k_attn<<<dim3(8 * 6 * 16, 1, 1), 256, 0, stream>>>(Qb, Kb, Vt, preScores,
                                                     maskPAD, scores_out, zp);
  k_oproj<<<dim3(64, 12), 256, 0, stream>>>(zp, Wo, bo, z_out);
}

// Round 12
// 169.232 us; speedup vs baseline: 1.1988x; 1.0733x over previous
//
#include <hip/hip_runtime.h>
#include <hip/hip_bf16.h>

#define B_ 4
#define L_ 1024
#define H_ 12
#define DK_ 64
#define FEA_ 768
#define MASKV (-32767.0f)

typedef __attribute__((ext_vector_type(8))) short bf16x8;
typedef __attribute__((ext_vector_type(4))) short s16x4;
typedef __attribute__((ext_vector_type(4))) float f32x4;
typedef unsigned int u32;

__device__ inline short f2bf(float x) {
  __hip_bfloat16 h = __float2bfloat16(x);   // HW cvt, RNE
  return __builtin_bit_cast(short, h);
}

// sizes (floats)
#define SZX  (4 * 1024 * 768)      // qx/kx/vx each: 3145728
#define SZW  (768 * 768)           // each W: 589824

// ---------------------------------------------------------------------------
// fp32 -> bf16 convert pass: qx,kx,vx,Wq,Wk,Wv -> contiguous bf16 scratch.
// (Wo handled by k_cvt2 after attn — its consumer runs post-attn and the
// scores-tail scratch is clobbered by then; R10's NaN was that lifetime bug.)
// ---------------------------------------------------------------------------
__global__ __launch_bounds__(256) void k_cvt(
    const float* __restrict__ qx, const float* __restrict__ kx,
    const float* __restrict__ vx,
    const float* __restrict__ Wq, const float* __restrict__ Wk,
    const float* __restrict__ Wv,
    unsigned short* __restrict__ dst)
{
  const size_t SZX4 = SZX / 4, SZW4 = SZW / 4;
  const size_t total4 = 3 * SZX4 + 3 * SZW4;
  for (size_t i4 = (size_t)blockIdx.x * 256 + threadIdx.x; i4 < total4;
       i4 += (size_t)gridDim.x * 256) {
    const float* src; size_t o4; size_t db;
    if (i4 < SZX4)               { src = qx; o4 = i4;               db = 0; }
    else if (i4 < 2 * SZX4)      { src = kx; o4 = i4 - SZX4;        db = (size_t)SZX; }
    else if (i4 < 3 * SZX4)      { src = vx; o4 = i4 - 2 * SZX4;    db = 2 * (size_t)SZX; }
    else if (i4 < 3 * SZX4 + SZW4)     { src = Wq; o4 = i4 - 3 * SZX4;            db = 3 * (size_t)SZX; }
    else if (i4 < 3 * SZX4 + 2 * SZW4) { src = Wk; o4 = i4 - 3 * SZX4 - SZW4;     db = 3 * (size_t)SZX + SZW; }
    else                               { src = Wv; o4 = i4 - 3 * SZX4 - 2 * SZW4; db = 3 * (size_t)SZX + 2 * (size_t)SZW; }
    float4 v = ((const float4*)src)[o4];
    s16x4 r = {f2bf(v.x), f2bf(v.y), f2bf(v.z), f2bf(v.w)};
    *(s16x4*)(dst + db + o4 * 4) = r;
  }
}

// ---------------------------------------------------------------------------
// Wo fp32 -> bf16, launched AFTER k_attn; dst aliases the then-dead Qb
// region in d_ws (stream-ordered, no extra scratch assumption).
// ---------------------------------------------------------------------------
__global__ __launch_bounds__(256) void k_cvt2(
    const float* __restrict__ Wo, unsigned short* __restrict__ dst)
{
  size_t i4 = (size_t)blockIdx.x * 256 + threadIdx.x;   // SZW/4 = 147456
  if (i4 < (size_t)SZW / 4) {
    float4 v = ((const float4*)Wo)[i4];
    s16x4 r = {f2bf(v.x), f2bf(v.y), f2bf(v.z), f2bf(v.w)};
    *(s16x4*)(dst + i4 * 4) = r;
  }
}

// ---------------------------------------------------------------------------
// QKV projection (pure bf16): out[m][n] = sum_k A[m][k]*W[n][k] + b[n].
// 64x64 tile, BK=64, 4 waves (2x2, each 32x32). global_load_lds staging
// (pre-swizzled source, linear LDS dest), dbuf 32KB. Grid (64,12,3).
// Q,K -> [b][h][l][d]; V -> [b][h][d][l] (epilogue s16x4-vectorized).
// ---------------------------------------------------------------------------
__global__ __launch_bounds__(256) void k_proj(
    const unsigned short* __restrict__ qxb, const unsigned short* __restrict__ kxb,
    const unsigned short* __restrict__ vxb,
    const unsigned short* __restrict__ Wqb, const unsigned short* __restrict__ Wkb,
    const unsigned short* __restrict__ Wvb,
    const float* __restrict__ bq, const float* __restrict__ bk,
    const float* __restrict__ bv,
    unsigned short* __restrict__ Qb, unsigned short* __restrict__ Kb,
    unsigned short* __restrict__ Vt)
{
  __shared__ short lA[2][64 * 64];
  __shared__ short lB[2][64 * 64];

  const int which = blockIdx.z;
  const unsigned short* __restrict__ Ab = (which == 0) ? qxb : (which == 1) ? kxb : vxb;
  const unsigned short* __restrict__ Wb = (which == 0) ? Wqb : (which == 1) ? Wkb : Wvb;
  const float* __restrict__ bias = (which == 0) ? bq : (which == 1) ? bk : bv;

  const int tid = threadIdx.x;
  const int lane = tid & 63;
  const int wid = tid >> 6;
  const int wr = wid >> 1, wc = wid & 1;
  const int m0 = blockIdx.x * 64;
  const int n0 = blockIdx.y * 64;
  const int g = lane >> 4, qc = lane & 15;
  const int srow = lane >> 3;
  const int spos = lane & 7;

#define PSTAGE(buf, ktof)                                                      \
  {                                                                            \
    _Pragma("unroll")                                                          \
    for (int i_ = 0; i_ < 2; i_++) {                                           \
      int r0_ = wid * 16 + i_ * 8;                                             \
      int row_ = r0_ + srow;                                                   \
      int cs_ = spos ^ (row_ & 7);                                             \
      __builtin_amdgcn_global_load_lds(                                        \
          (const __attribute__((address_space(1))) u32*)(Ab +                  \
              (size_t)(m0 + row_) * FEA_ + (ktof) + cs_ * 8),                  \
          (__attribute__((address_space(3))) u32*)&lA[buf][r0_ * 64],          \
          16, 0, 0);                                                           \
      __builtin_amdgcn_global_load_lds(                                        \
          (const __attribute__((address_space(1))) u32*)(Wb +                  \
              (size_t)(n0 + row_) * FEA_ + (ktof) + cs_ * 8),                  \
          (__attribute__((address_space(3))) u32*)&lB[buf][r0_ * 64],          \
          16, 0, 0);                                                           \
    }                                                                          \
  }

  f32x4 acc[2][2];
#pragma unroll
  for (int i = 0; i < 2; i++)
#pragma unroll
    for (int j = 0; j < 2; j++) acc[i][j] = f32x4{0.f, 0.f, 0.f, 0.f};

  PSTAGE(0, 0);
  asm volatile("s_waitcnt vmcnt(0)" ::: "memory");
  __builtin_amdgcn_s_barrier();

  for (int kt = 0; kt < 12; kt++) {
    const int cur = kt & 1, nxt = cur ^ 1;
    if (kt < 11) PSTAGE(nxt, (kt + 1) * 64);
    __builtin_amdgcn_sched_barrier(0);
    __builtin_amdgcn_s_setprio(1);
#pragma unroll
    for (int s = 0; s < 2; s++) {
      bf16x8 af[2], bfr[2];
#pragma unroll
      for (int i = 0; i < 2; i++) {
        int ar = wr * 32 + i * 16 + qc;
        af[i] = *(const bf16x8*)&lA[cur][ar * 64 + (((s * 4 + g) ^ (ar & 7)) << 3)];
        int br = wc * 32 + i * 16 + qc;
        bfr[i] = *(const bf16x8*)&lB[cur][br * 64 + (((s * 4 + g) ^ (br & 7)) << 3)];
      }
#pragma unroll
      for (int i = 0; i < 2; i++)
#pragma unroll
        for (int j = 0; j < 2; j++)
          acc[i][j] = __builtin_amdgcn_mfma_f32_16x16x32_bf16(af[i], bfr[j], acc[i][j], 0, 0, 0);
    }
    __builtin_amdgcn_s_setprio(0);
    asm volatile("s_waitcnt vmcnt(0)" ::: "memory");
    __builtin_amdgcn_s_barrier();
  }

  const int cn0 = n0 + wc * 32;
  float bv2[2];
#pragma unroll
  for (int j = 0; j < 2; j++) bv2[j] = bias[cn0 + j * 16 + qc];

#pragma unroll
  for (int i = 0; i < 2; i++) {
    int m = m0 + wr * 32 + i * 16 + g * 4;
    int bb = m >> 10;
    int l = m & 1023;
#pragma unroll
    for (int j = 0; j < 2; j++) {
      int n = cn0 + j * 16 + qc;
      int hh = n >> 6, d = n & 63;
      if (which == 2) {
        // V^T: 4 acc rows are consecutive l for fixed d -> one 8B store
        s16x4 vv = {f2bf(acc[i][j][0] + bv2[j]), f2bf(acc[i][j][1] + bv2[j]),
                    f2bf(acc[i][j][2] + bv2[j]), f2bf(acc[i][j][3] + bv2[j])};
        *(s16x4*)&Vt[(((size_t)bb * H_ + hh) * DK_ + d) * L_ + l] = vv;
      } else {
#pragma unroll
        for (int r = 0; r < 4; r++) {
          unsigned short v = (unsigned short)f2bf(acc[i][j][r] + bv2[j]);
          if (which == 0) {
            Qb[(((size_t)bb * H_ + hh) * L_ + (l + r)) * DK_ + d] = v;
          } else {
            Kb[(((size_t)bb * H_ + hh) * L_ + (l + r)) * DK_ + d] = v;
          }
        }
      }
    }
  }
#undef PSTAGE
}

// ---------------------------------------------------------------------------
// Fused attention v8 (FROZEN, verified R8/R11): R4 memory schedule + no-max
// softmax + XCD-aware block mapping + normal (L2-merged) scores stores.
// ---------------------------------------------------------------------------
__global__ __launch_bounds__(256, 3) void k_attn(
    const unsigned short* __restrict__ Qb, const unsigned short* __restrict__ Kb,
    const unsigned short* __restrict__ Vt,
    const float* __restrict__ preScores, const int* __restrict__ maskPAD,
    float* __restrict__ scoresOut, unsigned short* __restrict__ zp)
{
  __shared__ short lK[2][64 * 64];
  __shared__ short lV[2][64 * 64];
  __shared__ short lP[4][16 * 64];

  const int tid = threadIdx.x, lane = tid & 63, wid = tid >> 6;
  const int bi = blockIdx.x;
  const int slot = bi >> 3;                    // 0..95 within XCD
  const int bh_i = (bi & 7) * 6 + (slot >> 4); // 0..47
  const int qt = slot & 15;
  const int b = bh_i / H_;
  const int h = bh_i % H_;
  const int q0 = qt * 64;
  const int g = lane >> 4, qr = lane & 15;
  const int qrow = q0 + wid * 16 + qr;

  const size_t bh = (size_t)b * H_ + h;
  const unsigned short* __restrict__ Kbh = Kb + bh * L_ * DK_;
  const unsigned short* __restrict__ Vbh = Vt + bh * DK_ * L_;

  const int srow = lane >> 3;
  const int spos = lane & 7;

#define STAGE_KV(buf, kv0)                                                     \
  {                                                                            \
    _Pragma("unroll")                                                          \
    for (int i_ = 0; i_ < 2; i_++) {                                           \
      int r0_ = wid * 16 + i_ * 8;                                             \
      int row_ = r0_ + srow;                                                   \
      int cs_ = spos ^ (row_ & 7);                                             \
      __builtin_amdgcn_global_load_lds(                                        \
          (const __attribute__((address_space(1))) u32*)(Kbh +                 \
              (size_t)((kv0) + row_) * DK_ + cs_ * 8),                         \
          (__attribute__((address_space(3))) u32*)&lK[buf][r0_ * 64],          \
          16, 0, 0);                                                           \
      __builtin_amdgcn_global_load_lds(                                        \
          (const __attribute__((address_space(1))) u32*)(Vbh +                 \
              (size_t)row_ * L_ + (kv0) + cs_ * 8),                            \
          (__attribute__((address_space(3))) u32*)&lV[buf][r0_ * 64],          \
          16, 0, 0);                                                           \
    }                                                                          \
  }

  bf16x8 qf[2];
#pragma unroll
  for (int s = 0; s < 2; s++)
    qf[s] = *(const bf16x8*)(Qb + (bh * L_ + qrow) * DK_ + s * 32 + g * 8);

  f32x4 o[4];
#pragma unroll
  for (int i = 0; i < 4; i++) o[i] = f32x4{0.f, 0.f, 0.f, 0.f};
  float psum = 0.f;

  const size_t psBase = (bh * L_ + qrow) * L_;
  const size_t mkBase = ((size_t)b * L_ + qrow) * L_;

  STAGE_KV(0, 0);
  __builtin_amdgcn_sched_barrier(0);
  float4 psn[4];
  int4 mkn[4];
#pragma unroll
  for (int i = 0; i < 4; i++) {
    psn[i] = *(const float4*)(preScores + psBase + i * 16 + g * 4);
    mkn[i] = *(const int4*)(maskPAD + mkBase + i * 16 + g * 4);
  }
  asm volatile("s_waitcnt vmcnt(8)" ::: "memory");
  __builtin_amdgcn_s_barrier();

  for (int kt = 0; kt < 16; kt++) {
    const int kv0 = kt * 64;
    const int cur = kt & 1, nxt = cur ^ 1;

    if (kt < 15) {
      STAGE_KV(nxt, kv0 + 64);
    }
    __builtin_amdgcn_sched_barrier(0);

    float4 psc[4]; int4 mkc[4];
#pragma unroll
    for (int i = 0; i < 4; i++) { psc[i] = psn[i]; mkc[i] = mkn[i]; }
    if (kt < 15) {
#pragma unroll
      for (int i = 0; i < 4; i++) {
        psn[i] = *(const float4*)(preScores + psBase + kv0 + 64 + i * 16 + g * 4);
        mkn[i] = *(const int4*)(maskPAD + mkBase + kv0 + 64 + i * 16 + g * 4);
      }
    }

    f32x4 st[4];
#pragma unroll
    for (int i = 0; i < 4; i++) st[i] = f32x4{0.f, 0.f, 0.f, 0.f};
    __builtin_amdgcn_s_setprio(1);
#pragma unroll
    for (int s = 0; s < 2; s++) {
#pragma unroll
      for (int i = 0; i < 4; i++) {
        int kr = i * 16 + qr;
        bf16x8 kf = *(const bf16x8*)&lK[cur][kr * 64 + (((s * 4 + g) ^ (kr & 7)) << 3)];
        st[i] = __builtin_amdgcn_mfma_f32_16x16x32_bf16(kf, qf[s], st[i], 0, 0, 0);
      }
    }
    __builtin_amdgcn_s_setprio(0);

#pragma unroll
    for (int i = 0; i < 4; i++) {
      int ko = i * 16 + g * 4;
      float4 sv;
      sv.x = (mkc[i].x == 0) ? MASKV : st[i][0] * 0.125f + psc[i].x;
      sv.y = (mkc[i].y == 0) ? MASKV : st[i][1] * 0.125f + psc[i].y;
      sv.z = (mkc[i].z == 0) ? MASKV : st[i][2] * 0.125f + psc[i].z;
      sv.w = (mkc[i].w == 0) ? MASKV : st[i][3] * 0.125f + psc[i].w;
      *(float4*)(scoresOut + psBase + kv0 + ko) = sv;
      float p0 = __expf(sv.x);
      float p1 = __expf(sv.y);
      float p2 = __expf(sv.z);
      float p3 = __expf(sv.w);
      psum += (p0 + p1) + (p2 + p3);
      s16x4 pw = {f2bf(p0), f2bf(p1), f2bf(p2), f2bf(p3)};
      int c = i * 2 + (g >> 1);
      *(s16x4*)&lP[wid][qr * 64 + ((c ^ (qr & 7)) << 3) + ((g & 1) << 2)] = pw;
    }

    __builtin_amdgcn_s_setprio(1);
#pragma unroll
    for (int s = 0; s < 2; s++) {
      bf16x8 pf = *(const bf16x8*)&lP[wid][qr * 64 + (((s * 4 + g) ^ (qr & 7)) << 3)];
#pragma unroll
      for (int i = 0; i < 4; i++) {
        int vr = i * 16 + qr;
        bf16x8 vf = *(const bf16x8*)&lV[cur][vr * 64 + (((s * 4 + g) ^ (vr & 7)) << 3)];
        o[i] = __builtin_amdgcn_mfma_f32_16x16x32_bf16(vf, pf, o[i], 0, 0, 0);
      }
    }
    __builtin_amdgcn_s_setprio(0);

    asm volatile("s_waitcnt vmcnt(12)" ::: "memory");
    __builtin_amdgcn_s_barrier();
  }

  psum += __shfl_xor(psum, 16);
  psum += __shfl_xor(psum, 32);
  float inv = 1.f / psum;
  size_t zr = ((size_t)b * L_ + qrow) * FEA_ + (size_t)h * DK_;
#pragma unroll
  for (int i = 0; i < 4; i++) {
    s16x4 zw = {f2bf(o[i][0] * inv), f2bf(o[i][1] * inv),
                f2bf(o[i][2] * inv), f2bf(o[i][3] * inv)};
    *(s16x4*)((unsigned short*)zp + zr + i * 16 + g * 4) = zw;
  }
#undef STAGE_KV
}

// ---------------------------------------------------------------------------
// Output projection (pure bf16): out = zp @ Wob^T + bo, fp32 out.
// 64x64 tile, global_load_lds staging, dbuf 32KB. Grid (64,12).
// ---------------------------------------------------------------------------
__global__ __launch_bounds__(256) void k_oproj(
    const unsigned short* __restrict__ zp,
    const unsigned short* __restrict__ Wob, const float* __restrict__ bo,
    float* __restrict__ out)
{
  __shared__ short lA[2][64 * 64];
  __shared__ short lB[2][64 * 64];

  const int tid = threadIdx.x;
  const int lane = tid & 63;
  const int wid = tid >> 6;
  const int wr = wid >> 1, wc = wid & 1;
  const int m0 = blockIdx.x * 64;
  const int n0 = blockIdx.y * 64;
  const int g = lane >> 4, qc = lane & 15;
  const int srow = lane >> 3;
  const int spos = lane & 7;

#define OSTAGE(buf, ktof)                                                      \
  {                                                                            \
    _Pragma("unroll")                                                          \
    for (int i_ = 0; i_ < 2; i_++) {                                           \
      int r0_ = wid * 16 + i_ * 8;                                             \
      int row_ = r0_ + srow;                                                   \
      int cs_ = spos ^ (row_ & 7);                                             \
      __builtin_amdgcn_global_load_lds(                                        \
          (const __attribute__((address_space(1))) u32*)(zp +                  \
              (size_t)(m0 + row_) * FEA_ + (ktof) + cs_ * 8),                  \
          (__attribute__((address_space(3))) u32*)&lA[buf][r0_ * 64],          \
          16, 0, 0);                                                           \
      __builtin_amdgcn_global_load_lds(                                        \
          (const __attribute__((address_space(1))) u32*)(Wob +                 \
              (size_t)(n0 + row_) * FEA_ + (ktof) + cs_ * 8),                  \
          (__attribute__((address_space(3))) u32*)&lB[buf][r0_ * 64],          \
          16, 0, 0);                                                           \
    }                                                                          \
  }

  f32x4 acc[2][2];
#pragma unroll
  for (int i = 0; i < 2; i++)
#pragma unroll
    for (int j = 0; j < 2; j++) acc[i][j] = f32x4{0.f, 0.f, 0.f, 0.f};

  OSTAGE(0, 0);
  asm volatile("s_waitcnt vmcnt(0)" ::: "memory");
  __builtin_amdgcn_s_barrier();

  for (int kt = 0; kt < 12; kt++) {
    const int cur = kt & 1, nxt = cur ^ 1;
    if (kt < 11) OSTAGE(nxt, (kt + 1) * 64);
    __builtin_amdgcn_sched_barrier(0);
    __builtin_amdgcn_s_setprio(1);
#pragma unroll
    for (int s = 0; s < 2; s++) {
      bf16x8 af[2], bfr[2];
#pragma unroll
      for (int i = 0; i < 2; i++) {
        int ar = wr * 32 + i * 16 + qc;
        af[i] = *(const bf16x8*)&lA[cur][ar * 64 + (((s * 4 + g) ^ (ar & 7)) << 3)];
        int br = wc * 32 + i * 16 + qc;
        bfr[i] = *(const bf16x8*)&lB[cur][br * 64 + (((s * 4 + g) ^ (br & 7)) << 3)];
      }
#pragma unroll
      for (int i = 0; i < 2; i++)
#pragma unroll
        for (int j = 0; j < 2; j++)
          acc[i][j] = __builtin_amdgcn_mfma_f32_16x16x32_bf16(af[i], bfr[j], acc[i][j], 0, 0, 0);
    }
    __builtin_amdgcn_s_setprio(0);
    asm volatile("s_waitcnt vmcnt(0)" ::: "memory");
    __builtin_amdgcn_s_barrier();
  }

  const int cn0 = n0 + wc * 32;
  float bv2[2];
#pragma unroll
  for (int j = 0; j < 2; j++) bv2[j] = bo[cn0 + j * 16 + qc];

#pragma unroll
  for (int i = 0; i < 2; i++) {
    int m = m0 + wr * 32 + i * 16 + g * 4;
#pragma unroll
    for (int j = 0; j < 2; j++) {
      int n = cn0 + j * 16 + qc;
#pragma unroll
      for (int r = 0; r < 4; r++) {
        out[(size_t)(m + r) * FEA_ + n] = acc[i][j][r] + bv2[j];
      }
    }
  }
#undef OSTAGE
}

extern "C" void kernel_launch(void* const* d_in, const int* in_sizes, int n_in,
                              void* d_out, int out_size, void* d_ws, size_t ws_size,
                              hipStream_t stream) {
  const float* qx = (const float*)d_in[0];
  const float* kx = (const float*)d_in[1];
  const float* vx = (const float*)d_in[2];
  const float* preScores = (const float*)d_in[3];
  const int* maskPAD = (const int*)d_in[4];
  const float* Wq = (const float*)d_in[5];
  const float* bq = (const float*)d_in[6];
  const float* Wk = (const float*)d_in[7];
  const float* bk = (const float*)d_in[8];
  const float* Wv = (const float*)d_in[9];
  const float* bv = (const float*)d_in[10];
  const float* Wo = (const float*)d_in[11];
  const float* bo = (const float*)d_in[12];

  float* z_out = (float*)d_out;
  float* scores_out = z_out + (size_t)B_ * L_ * FEA_;

  unsigned short* Qb = (unsigned short*)d_ws;
  unsigned short* Kb = Qb + (size_t)B_ * H_ * L_ * DK_;
  unsigned short* Vt = Kb + (size_t)B_ * H_ * L_ * DK_;
  unsigned short* zp = Vt + (size_t)B_ * H_ * L_ * DK_;

  // bf16 scratch carved from the TAIL of the scores output region. Holds
  // ONLY tensors consumed by k_proj (k_proj completes before k_attn's
  // scores writes clobber it). 11206656 shorts = 5603328 floats.
  unsigned short* cvtb = (unsigned short*)(scores_out + (50331648 - 5603328));
  const unsigned short* qxb = cvtb;
  const unsigned short* kxb = cvtb + (size_t)SZX;
  const unsigned short* vxb = cvtb + 2 * (size_t)SZX;
  const unsigned short* Wqb = cvtb + 3 * (size_t)SZX;
  const unsigned short* Wkb = cvtb + 3 * (size_t)SZX + (size_t)SZW;
  const unsigned short* Wvb = cvtb + 3 * (size_t)SZX + 2 * (size_t)SZW;

  // Wo bf16 aliases the Qb region (dead after k_attn); written post-attn.
  unsigned short* Wob = Qb;

  k_cvt<<<dim3(1024), 256, 0, stream>>>(qx, kx, vx, Wq, Wk, Wv, cvtb);
  k_proj<<<dim3(64, 12, 3), 256, 0, stream>>>(qxb, kxb, vxb, Wqb, Wkb, Wvb,
                                              bq, bk, bv, Qb, Kb, Vt);
  k_attn<<<dim3(8 * 6 * 16, 1, 1), 256, 0, stream>>>(Qb, Kb, Vt, preScores,
                                                     maskPAD, scores_out, zp);
  k_cvt2<<<dim3(576), 256, 0, stream>>>(Wo, Wob);
  k_oproj<<<dim3(64, 12), 256, 0, stream>>>(zp, Wob, bo, z_out);
}

// Round 13
// 159.162 us; speedup vs baseline: 1.2746x; 1.0633x over previous
//
#include <hip/hip_runtime.h>
#include <hip/hip_bf16.h>

#define B_ 4
#define L_ 1024
#define H_ 12
#define DK_ 64
#define FEA_ 768
#define MASKV (-32767.0f)

typedef __attribute__((ext_vector_type(8))) short bf16x8;
typedef __attribute__((ext_vector_type(4))) short s16x4;
typedef __attribute__((ext_vector_type(4))) float f32x4;
typedef unsigned int u32;

__device__ inline short f2bf(float x) {
  __hip_bfloat16 h = __float2bfloat16(x);   // HW cvt, RNE
  return __builtin_bit_cast(short, h);
}

// sizes (floats)
#define SZX  (4 * 1024 * 768)      // qx/kx/vx each: 3145728
#define SZW  (768 * 768)           // each W: 589824

// ---------------------------------------------------------------------------
// fp32 -> bf16 convert pass: qx,kx,vx,Wq,Wk,Wv -> contiguous bf16 scratch.
// ---------------------------------------------------------------------------
__global__ __launch_bounds__(256) void k_cvt(
    const float* __restrict__ qx, const float* __restrict__ kx,
    const float* __restrict__ vx,
    const float* __restrict__ Wq, const float* __restrict__ Wk,
    const float* __restrict__ Wv,
    unsigned short* __restrict__ dst)
{
  const size_t SZX4 = SZX / 4, SZW4 = SZW / 4;
  const size_t total4 = 3 * SZX4 + 3 * SZW4;
  for (size_t i4 = (size_t)blockIdx.x * 256 + threadIdx.x; i4 < total4;
       i4 += (size_t)gridDim.x * 256) {
    const float* src; size_t o4; size_t db;
    if (i4 < SZX4)               { src = qx; o4 = i4;               db = 0; }
    else if (i4 < 2 * SZX4)      { src = kx; o4 = i4 - SZX4;        db = (size_t)SZX; }
    else if (i4 < 3 * SZX4)      { src = vx; o4 = i4 - 2 * SZX4;    db = 2 * (size_t)SZX; }
    else if (i4 < 3 * SZX4 + SZW4)     { src = Wq; o4 = i4 - 3 * SZX4;            db = 3 * (size_t)SZX; }
    else if (i4 < 3 * SZX4 + 2 * SZW4) { src = Wk; o4 = i4 - 3 * SZX4 - SZW4;     db = 3 * (size_t)SZX + SZW; }
    else                               { src = Wv; o4 = i4 - 3 * SZX4 - 2 * SZW4; db = 3 * (size_t)SZX + 2 * (size_t)SZW; }
    float4 v = ((const float4*)src)[o4];
    s16x4 r = {f2bf(v.x), f2bf(v.y), f2bf(v.z), f2bf(v.w)};
    *(s16x4*)(dst + db + o4 * 4) = r;
  }
}

// ---------------------------------------------------------------------------
// Wo fp32 -> bf16, launched AFTER k_attn; dst aliases the then-dead Qb region.
// ---------------------------------------------------------------------------
__global__ __launch_bounds__(256) void k_cvt2(
    const float* __restrict__ Wo, unsigned short* __restrict__ dst)
{
  size_t i4 = (size_t)blockIdx.x * 256 + threadIdx.x;
  if (i4 < (size_t)SZW / 4) {
    float4 v = ((const float4*)Wo)[i4];
    s16x4 r = {f2bf(v.x), f2bf(v.y), f2bf(v.z), f2bf(v.w)};
    *(s16x4*)(dst + i4 * 4) = r;
  }
}

// ---------------------------------------------------------------------------
// QKV projection (pure bf16, verified R11/R12).
// ---------------------------------------------------------------------------
__global__ __launch_bounds__(256) void k_proj(
    const unsigned short* __restrict__ qxb, const unsigned short* __restrict__ kxb,
    const unsigned short* __restrict__ vxb,
    const unsigned short* __restrict__ Wqb, const unsigned short* __restrict__ Wkb,
    const unsigned short* __restrict__ Wvb,
    const float* __restrict__ bq, const float* __restrict__ bk,
    const float* __restrict__ bv,
    unsigned short* __restrict__ Qb, unsigned short* __restrict__ Kb,
    unsigned short* __restrict__ Vt)
{
  __shared__ short lA[2][64 * 64];
  __shared__ short lB[2][64 * 64];

  const int which = blockIdx.z;
  const unsigned short* __restrict__ Ab = (which == 0) ? qxb : (which == 1) ? kxb : vxb;
  const unsigned short* __restrict__ Wb = (which == 0) ? Wqb : (which == 1) ? Wkb : Wvb;
  const float* __restrict__ bias = (which == 0) ? bq : (which == 1) ? bk : bv;

  const int tid = threadIdx.x;
  const int lane = tid & 63;
  const int wid = tid >> 6;
  const int wr = wid >> 1, wc = wid & 1;
  const int m0 = blockIdx.x * 64;
  const int n0 = blockIdx.y * 64;
  const int g = lane >> 4, qc = lane & 15;
  const int srow = lane >> 3;
  const int spos = lane & 7;

#define PSTAGE(buf, ktof)                                                      \
  {                                                                            \
    _Pragma("unroll")                                                          \
    for (int i_ = 0; i_ < 2; i_++) {                                           \
      int r0_ = wid * 16 + i_ * 8;                                             \
      int row_ = r0_ + srow;                                                   \
      int cs_ = spos ^ (row_ & 7);                                             \
      __builtin_amdgcn_global_load_lds(                                        \
          (const __attribute__((address_space(1))) u32*)(Ab +                  \
              (size_t)(m0 + row_) * FEA_ + (ktof) + cs_ * 8),                  \
          (__attribute__((address_space(3))) u32*)&lA[buf][r0_ * 64],          \
          16, 0, 0);                                                           \
      __builtin_amdgcn_global_load_lds(                                        \
          (const __attribute__((address_space(1))) u32*)(Wb +                  \
              (size_t)(n0 + row_) * FEA_ + (ktof) + cs_ * 8),                  \
          (__attribute__((address_space(3))) u32*)&lB[buf][r0_ * 64],          \
          16, 0, 0);                                                           \
    }                                                                          \
  }

  f32x4 acc[2][2];
#pragma unroll
  for (int i = 0; i < 2; i++)
#pragma unroll
    for (int j = 0; j < 2; j++) acc[i][j] = f32x4{0.f, 0.f, 0.f, 0.f};

  PSTAGE(0, 0);
  asm volatile("s_waitcnt vmcnt(0)" ::: "memory");
  __builtin_amdgcn_s_barrier();

  for (int kt = 0; kt < 12; kt++) {
    const int cur = kt & 1, nxt = cur ^ 1;
    if (kt < 11) PSTAGE(nxt, (kt + 1) * 64);
    __builtin_amdgcn_sched_barrier(0);
    __builtin_amdgcn_s_setprio(1);
#pragma unroll
    for (int s = 0; s < 2; s++) {
      bf16x8 af[2], bfr[2];
#pragma unroll
      for (int i = 0; i < 2; i++) {
        int ar = wr * 32 + i * 16 + qc;
        af[i] = *(const bf16x8*)&lA[cur][ar * 64 + (((s * 4 + g) ^ (ar & 7)) << 3)];
        int br = wc * 32 + i * 16 + qc;
        bfr[i] = *(const bf16x8*)&lB[cur][br * 64 + (((s * 4 + g) ^ (br & 7)) << 3)];
      }
#pragma unroll
      for (int i = 0; i < 2; i++)
#pragma unroll
        for (int j = 0; j < 2; j++)
          acc[i][j] = __builtin_amdgcn_mfma_f32_16x16x32_bf16(af[i], bfr[j], acc[i][j], 0, 0, 0);
    }
    __builtin_amdgcn_s_setprio(0);
    asm volatile("s_waitcnt vmcnt(0)" ::: "memory");
    __builtin_amdgcn_s_barrier();
  }

  const int cn0 = n0 + wc * 32;
  float bv2[2];
#pragma unroll
  for (int j = 0; j < 2; j++) bv2[j] = bias[cn0 + j * 16 + qc];

#pragma unroll
  for (int i = 0; i < 2; i++) {
    int m = m0 + wr * 32 + i * 16 + g * 4;
    int bb = m >> 10;
    int l = m & 1023;
#pragma unroll
    for (int j = 0; j < 2; j++) {
      int n = cn0 + j * 16 + qc;
      int hh = n >> 6, d = n & 63;
      if (which == 2) {
        s16x4 vv = {f2bf(acc[i][j][0] + bv2[j]), f2bf(acc[i][j][1] + bv2[j]),
                    f2bf(acc[i][j][2] + bv2[j]), f2bf(acc[i][j][3] + bv2[j])};
        *(s16x4*)&Vt[(((size_t)bb * H_ + hh) * DK_ + d) * L_ + l] = vv;
      } else {
#pragma unroll
        for (int r = 0; r < 4; r++) {
          unsigned short v = (unsigned short)f2bf(acc[i][j][r] + bv2[j]);
          if (which == 0) {
            Qb[(((size_t)bb * H_ + hh) * L_ + (l + r)) * DK_ + d] = v;
          } else {
            Kb[(((size_t)bb * H_ + hh) * L_ + (l + r)) * DK_ + d] = v;
          }
        }
      }
    }
  }
#undef PSTAGE
}

// ---------------------------------------------------------------------------
// Fused attention v9: R8 schedule + COALESCED ps/mask/scores lanes.
// ps/mask/scores instructions now cover 4 rows x 256B contiguous (was 16 rows
// x 64B). QK^T result bridged MFMA-layout -> coalesced-layout via wave-private
// LDS bounce (lU). lP (P-matrix for PV) aliases the head of lU (lS dead by
// the time p is written; all st reads complete before first p write).
// ---------------------------------------------------------------------------
__global__ __launch_bounds__(256, 3) void k_attn(
    const unsigned short* __restrict__ Qb, const unsigned short* __restrict__ Kb,
    const unsigned short* __restrict__ Vt,
    const float* __restrict__ preScores, const int* __restrict__ maskPAD,
    float* __restrict__ scoresOut, unsigned short* __restrict__ zp)
{
  __shared__ short lK[2][64 * 64];
  __shared__ short lV[2][64 * 64];
  __shared__ float lU[4][1120];   // per wave: [0..1087] st spill 16x68 f32;
                                  // lP aliases bytes 0..2047; [1088..1103] row sums

  const int tid = threadIdx.x, lane = tid & 63, wid = tid >> 6;
  const int bi = blockIdx.x;
  const int slot = bi >> 3;
  const int bh_i = (bi & 7) * 6 + (slot >> 4);
  const int qt = slot & 15;
  const int b = bh_i / H_;
  const int h = bh_i % H_;
  const int q0 = qt * 64;
  const int g = lane >> 4, qr = lane & 15;
  const int qrow = q0 + wid * 16 + qr;      // MFMA-layout row
  const int rhi = lane >> 4, klo = lane & 15;  // coalesced roles
  const int rowCg = q0 + wid * 16 + rhi;    // coalesced-layout global row

  const size_t bh = (size_t)b * H_ + h;
  const unsigned short* __restrict__ Kbh = Kb + bh * L_ * DK_;
  const unsigned short* __restrict__ Vbh = Vt + bh * DK_ * L_;

  float* lSw = &lU[wid][0];
  short* lPw = (short*)&lU[wid][0];
  float* lLw = &lU[wid][1088];

  const int srow = lane >> 3;
  const int spos = lane & 7;

#define STAGE_KV(buf, kv0)                                                     \
  {                                                                            \
    _Pragma("unroll")                                                          \
    for (int i_ = 0; i_ < 2; i_++) {                                           \
      int r0_ = wid * 16 + i_ * 8;                                             \
      int row_ = r0_ + srow;                                                   \
      int cs_ = spos ^ (row_ & 7);                                             \
      __builtin_amdgcn_global_load_lds(                                        \
          (const __attribute__((address_space(1))) u32*)(Kbh +                 \
              (size_t)((kv0) + row_) * DK_ + cs_ * 8),                         \
          (__attribute__((address_space(3))) u32*)&lK[buf][r0_ * 64],          \
          16, 0, 0);                                                           \
      __builtin_amdgcn_global_load_lds(                                        \
          (const __attribute__((address_space(1))) u32*)(Vbh +                 \
              (size_t)row_ * L_ + (kv0) + cs_ * 8),                            \
          (__attribute__((address_space(3))) u32*)&lV[buf][r0_ * 64],          \
          16, 0, 0);                                                           \
    }                                                                          \
  }

  bf16x8 qf[2];
#pragma unroll
  for (int s = 0; s < 2; s++)
    qf[s] = *(const bf16x8*)(Qb + (bh * L_ + qrow) * DK_ + s * 32 + g * 8);

  f32x4 o[4];
#pragma unroll
  for (int i = 0; i < 4; i++) o[i] = f32x4{0.f, 0.f, 0.f, 0.f};
  float psum[4] = {0.f, 0.f, 0.f, 0.f};   // per coalesced row (4j+rhi)

  // coalesced stream bases: 16 lanes (klo) cover one row contiguously;
  // j in 0..3 steps rows by 4 (offset j*4*L_ = j*4096 floats).
  const size_t psCbase = (bh * L_ + rowCg) * L_ + klo * 4;
  const size_t mkCbase = ((size_t)b * L_ + rowCg) * L_ + klo * 4;

  STAGE_KV(0, 0);
  __builtin_amdgcn_sched_barrier(0);
  float4 psn[4];
  int4 mkn[4];
#pragma unroll
  for (int j = 0; j < 4; j++) {
    psn[j] = *(const float4*)(preScores + psCbase + j * 4096);
    mkn[j] = *(const int4*)(maskPAD + mkCbase + j * 4096);
  }
  asm volatile("s_waitcnt vmcnt(8)" ::: "memory");
  __builtin_amdgcn_s_barrier();

  for (int kt = 0; kt < 16; kt++) {
    const int kv0 = kt * 64;
    const int cur = kt & 1, nxt = cur ^ 1;

    if (kt < 15) {
      STAGE_KV(nxt, kv0 + 64);
    }
    __builtin_amdgcn_sched_barrier(0);

    float4 psc[4]; int4 mkc[4];
#pragma unroll
    for (int j = 0; j < 4; j++) { psc[j] = psn[j]; mkc[j] = mkn[j]; }
    if (kt < 15) {
#pragma unroll
      for (int j = 0; j < 4; j++) {
        psn[j] = *(const float4*)(preScores + psCbase + kv0 + 64 + j * 4096);
        mkn[j] = *(const int4*)(maskPAD + mkCbase + kv0 + 64 + j * 4096);
      }
    }

    // S^T = K . Q^T from LDS (MFMA layout: lane g*16+qr owns row qr,
    // keys i*16+g*4..+3)
    f32x4 st[4];
#pragma unroll
    for (int i = 0; i < 4; i++) st[i] = f32x4{0.f, 0.f, 0.f, 0.f};
    __builtin_amdgcn_s_setprio(1);
#pragma unroll
    for (int s = 0; s < 2; s++) {
#pragma unroll
      for (int i = 0; i < 4; i++) {
        int kr = i * 16 + qr;
        bf16x8 kf = *(const bf16x8*)&lK[cur][kr * 64 + (((s * 4 + g) ^ (kr & 7)) << 3)];
        st[i] = __builtin_amdgcn_mfma_f32_16x16x32_bf16(kf, qf[s], st[i], 0, 0, 0);
      }
    }
    __builtin_amdgcn_s_setprio(0);

    // bridge MFMA layout -> coalesced layout through wave-private LDS
#pragma unroll
    for (int i = 0; i < 4; i++)
      *(f32x4*)&lSw[qr * 68 + i * 16 + g * 4] = st[i];
    f32x4 stc[4];
#pragma unroll
    for (int j = 0; j < 4; j++)
      stc[j] = *(const f32x4*)&lSw[(4 * j + rhi) * 68 + klo * 4];

    // coalesced: scale + ps + mask; 256B-contiguous scores store; exp;
    // per-row psum; pack p into lP (aliases lS head — all stc reads done).
#pragma unroll
    for (int j = 0; j < 4; j++) {
      float4 sv;
      sv.x = (mkc[j].x == 0) ? MASKV : stc[j][0] * 0.125f + psc[j].x;
      sv.y = (mkc[j].y == 0) ? MASKV : stc[j][1] * 0.125f + psc[j].y;
      sv.z = (mkc[j].z == 0) ? MASKV : stc[j][2] * 0.125f + psc[j].z;
      sv.w = (mkc[j].w == 0) ? MASKV : stc[j][3] * 0.125f + psc[j].w;
      *(float4*)(scoresOut + psCbase + kv0 + j * 4096) = sv;
      float p0 = __expf(sv.x);
      float p1 = __expf(sv.y);
      float p2 = __expf(sv.z);
      float p3 = __expf(sv.w);
      psum[j] += (p0 + p1) + (p2 + p3);
      s16x4 pw = {f2bf(p0), f2bf(p1), f2bf(p2), f2bf(p3)};
      int rL = 4 * j + rhi;
      int c = klo >> 1, sub = (klo & 1) * 4;
      *(s16x4*)&lPw[rL * 64 + ((c ^ (rL & 7)) << 3) + sub] = pw;
    }

    // O^T += Vt_strip . P^T from LDS
    __builtin_amdgcn_s_setprio(1);
#pragma unroll
    for (int s = 0; s < 2; s++) {
      bf16x8 pf = *(const bf16x8*)&lPw[qr * 64 + (((s * 4 + g) ^ (qr & 7)) << 3)];
#pragma unroll
      for (int i = 0; i < 4; i++) {
        int vr = i * 16 + qr;
        bf16x8 vf = *(const bf16x8*)&lV[cur][vr * 64 + (((s * 4 + g) ^ (vr & 7)) << 3)];
        o[i] = __builtin_amdgcn_mfma_f32_16x16x32_bf16(vf, pf, o[i], 0, 0, 0);
      }
    }
    __builtin_amdgcn_s_setprio(0);

    asm volatile("s_waitcnt vmcnt(12)" ::: "memory");
    __builtin_amdgcn_s_barrier();
  }

  // per-row sums: reduce over the 16 klo lanes, publish via lLw, normalize.
#pragma unroll
  for (int j = 0; j < 4; j++) {
    float v = psum[j];
    v += __shfl_xor(v, 1);
    v += __shfl_xor(v, 2);
    v += __shfl_xor(v, 4);
    v += __shfl_xor(v, 8);
    if (klo == 0) lLw[4 * j + rhi] = v;
  }
  float inv = 1.f / lLw[qr];
  size_t zr = ((size_t)b * L_ + qrow) * FEA_ + (size_t)h * DK_;
#pragma unroll
  for (int i = 0; i < 4; i++) {
    s16x4 zw = {f2bf(o[i][0] * inv), f2bf(o[i][1] * inv),
                f2bf(o[i][2] * inv), f2bf(o[i][3] * inv)};
    *(s16x4*)((unsigned short*)zp + zr + i * 16 + g * 4) = zw;
  }
#undef STAGE_KV
}

// ---------------------------------------------------------------------------
// Output projection (pure bf16, verified R12).
// ---------------------------------------------------------------------------
__global__ __launch_bounds__(256) void k_oproj(
    const unsigned short* __restrict__ zp,
    const unsigned short* __restrict__ Wob, const float* __restrict__ bo,
    float* __restrict__ out)
{
  __shared__ short lA[2][64 * 64];
  __shared__ short lB[2][64 * 64];

  const int tid = threadIdx.x;
  const int lane = tid & 63;
  const int wid = tid >> 6;
  const int wr = wid >> 1, wc = wid & 1;
  const int m0 = blockIdx.x * 64;
  const int n0 = blockIdx.y * 64;
  const int g = lane >> 4, qc = lane & 15;
  const int srow = lane >> 3;
  const int spos = lane & 7;

#define OSTAGE(buf, ktof)                                                      \
  {                                                                            \
    _Pragma("unroll")                                                          \
    for (int i_ = 0; i_ < 2; i_++) {                                           \
      int r0_ = wid * 16 + i_ * 8;                                             \
      int row_ = r0_ + srow;                                                   \
      int cs_ = spos ^ (row_ & 7);                                             \
      __builtin_amdgcn_global_load_lds(                                        \
          (const __attribute__((address_space(1))) u32*)(zp +                  \
              (size_t)(m0 + row_) * FEA_ + (ktof) + cs_ * 8),                  \
          (__attribute__((address_space(3))) u32*)&lA[buf][r0_ * 64],          \
          16, 0, 0);                                                           \
      __builtin_amdgcn_global_load_lds(                                        \
          (const __attribute__((address_space(1))) u32*)(Wob +                 \
              (size_t)(n0 + row_) * FEA_ + (ktof) + cs_ * 8),                  \
          (__attribute__((address_space(3))) u32*)&lB[buf][r0_ * 64],          \
          16, 0, 0);                                                           \
    }                                                                          \
  }

  f32x4 acc[2][2];
#pragma unroll
  for (int i = 0; i < 2; i++)
#pragma unroll
    for (int j = 0; j < 2; j++) acc[i][j] = f32x4{0.f, 0.f, 0.f, 0.f};

  OSTAGE(0, 0);
  asm volatile("s_waitcnt vmcnt(0)" ::: "memory");
  __builtin_amdgcn_s_barrier();

  for (int kt = 0; kt < 12; kt++) {
    const int cur = kt & 1, nxt = cur ^ 1;
    if (kt < 11) OSTAGE(nxt, (kt + 1) * 64);
    __builtin_amdgcn_sched_barrier(0);
    __builtin_amdgcn_s_setprio(1);
#pragma unroll
    for (int s = 0; s < 2; s++) {
      bf16x8 af[2], bfr[2];
#pragma unroll
      for (int i = 0; i < 2; i++) {
        int ar = wr * 32 + i * 16 + qc;
        af[i] = *(const bf16x8*)&lA[cur][ar * 64 + (((s * 4 + g) ^ (ar & 7)) << 3)];
        int br = wc * 32 + i * 16 + qc;
        bfr[i] = *(const bf16x8*)&lB[cur][br * 64 + (((s * 4 + g) ^ (br & 7)) << 3)];
      }
#pragma unroll
      for (int i = 0; i < 2; i++)
#pragma unroll
        for (int j = 0; j < 2; j++)
          acc[i][j] = __builtin_amdgcn_mfma_f32_16x16x32_bf16(af[i], bfr[j], acc[i][j], 0, 0, 0);
    }
    __builtin_amdgcn_s_setprio(0);
    asm volatile("s_waitcnt vmcnt(0)" ::: "memory");
    __builtin_amdgcn_s_barrier();
  }

  const int cn0 = n0 + wc * 32;
  float bv2[2];
#pragma unroll
  for (int j = 0; j < 2; j++) bv2[j] = bo[cn0 + j * 16 + qc];

#pragma unroll
  for (int i = 0; i < 2; i++) {
    int m = m0 + wr * 32 + i * 16 + g * 4;
#pragma unroll
    for (int j = 0; j < 2; j++) {
      int n = cn0 + j * 16 + qc;
#pragma unroll
      for (int r = 0; r < 4; r++) {
        out[(size_t)(m + r) * FEA_ + n] = acc[i][j][r] + bv2[j];
      }
    }
  }
#undef OSTAGE
}

extern "C" void kernel_launch(void* const* d_in, const int* in_sizes, int n_in,
                              void* d_out, int out_size, void* d_ws, size_t ws_size,
                              hipStream_t stream) {
  const float* qx = (const float*)d_in[0];
  const float* kx = (const float*)d_in[1];
  const float* vx = (const float*)d_in[2];
  const float* preScores = (const float*)d_in[3];
  const int* maskPAD = (const int*)d_in[4];
  const float* Wq = (const float*)d_in[5];
  const float* bq = (const float*)d_in[6];
  const float* Wk = (const float*)d_in[7];
  const float* bk = (const float*)d_in[8];
  const float* Wv = (const float*)d_in[9];
  const float* bv = (const float*)d_in[10];
  const float* Wo = (const float*)d_in[11];
  const float* bo = (const float*)d_in[12];

  float* z_out = (float*)d_out;
  float* scores_out = z_out + (size_t)B_ * L_ * FEA_;

  unsigned short* Qb = (unsigned short*)d_ws;
  unsigned short* Kb = Qb + (size_t)B_ * H_ * L_ * DK_;
  unsigned short* Vt = Kb + (size_t)B_ * H_ * L_ * DK_;
  unsigned short* zp = Vt + (size_t)B_ * H_ * L_ * DK_;

  unsigned short* cvtb = (unsigned short*)(scores_out + (50331648 - 5603328));
  const unsigned short* qxb = cvtb;
  const unsigned short* kxb = cvtb + (size_t)SZX;
  const unsigned short* vxb = cvtb + 2 * (size_t)SZX;
  const unsigned short* Wqb = cvtb + 3 * (size_t)SZX;
  const unsigned short* Wkb = cvtb + 3 * (size_t)SZX + (size_t)SZW;
  const unsigned short* Wvb = cvtb + 3 * (size_t)SZX + 2 * (size_t)SZW;

  unsigned short* Wob = Qb;   // dead after k_attn

  k_cvt<<<dim3(1024), 256, 0, stream>>>(qx, kx, vx, Wq, Wk, Wv, cvtb);
  k_proj<<<dim3(64, 12, 3), 256, 0, stream>>>(qxb, kxb, vxb, Wqb, Wkb, Wvb,
                                              bq, bk, bv, Qb, Kb, Vt);
  k_attn<<<dim3(8 * 6 * 16, 1, 1), 256, 0, stream>>>(Qb, Kb, Vt, preScores,
                                                     maskPAD, scores_out, zp);
  k_cvt2<<<dim3(576), 256, 0, stream>>>(Wo, Wob);
  k_oproj<<<dim3(64, 12), 256, 0, stream>>>(zp, Wob, bo, z_out);
}